// Round 8
// baseline (1562.480 us; speedup 1.0000x reference)
//
#include <hip/hip_runtime.h>
#include <hip/hip_bf16.h>
#include <cstdint>
#include <cstddef>

#define M_DIM 8192
#define K_DIM 4096
#define N_DIM 4096

typedef __bf16 bf16x8 __attribute__((ext_vector_type(8)));
typedef float  f32x4  __attribute__((ext_vector_type(4)));

__device__ __forceinline__ unsigned short f32_to_bf16_rne(float f) {
  unsigned int u = __builtin_bit_cast(unsigned int, f);
  u += 0x7FFFu + ((u >> 16) & 1u);
  return (unsigned short)(u >> 16);
}

// Single fused fp32->bf16 conversion for both A and W (one launch).
__global__ void __launch_bounds__(256) cvt_both(const float* __restrict__ A,
                                                const float* __restrict__ W,
                                                unsigned short* __restrict__ Abf,
                                                unsigned short* __restrict__ Wbf,
                                                int a4, int tot4) {
  int i = blockIdx.x * blockDim.x + threadIdx.x;
  int stride = gridDim.x * blockDim.x;
  for (; i < tot4; i += stride) {
    const float4* s = (i < a4) ? &reinterpret_cast<const float4*>(A)[i]
                               : &reinterpret_cast<const float4*>(W)[i - a4];
    ushort4* d = (i < a4) ? &reinterpret_cast<ushort4*>(Abf)[i]
                          : &reinterpret_cast<ushort4*>(Wbf)[i - a4];
    float4 v = *s;
    ushort4 o;
    o.x = f32_to_bf16_rne(v.x);
    o.y = f32_to_bf16_rne(v.y);
    o.z = f32_to_bf16_rne(v.z);
    o.w = f32_to_bf16_rne(v.w);
    *d = o;
  }
}

__device__ __forceinline__ void gload16(const void* g, void* l) {
  __builtin_amdgcn_global_load_lds((const __attribute__((address_space(1))) void*)g,
                                   (__attribute__((address_space(3))) void*)l, 16, 0, 0);
}

// 256x256-tile, BK=32, 8-wave (2Mx4N), single-window-per-K-tile GEMM.
//
// ROUND-8 CHANGE (evidence: r7 MfmaUtil 59.5 with Occupancy 21.7 = 1 block/CU
// at 128 KiB LDS; window wall 2025 cyc vs 1242 MFMA-busy -> intra-block
// fill/drain that one resident block cannot hide): LDS halved to 64 KiB
// (BK 64->32, 2buf x (A 16K + B 16K)) -> 2 blocks/CU. Cross-block overlap
// hides barrier/gate stalls (m97 mechanism), on top of T1/T2/T19/T5.
//
// Window k (cur = k&1): { STAGE4(tile k+1 -> buf cur^1)  [4 gload_lds, issued
// FIRST: longest latency]; LDB4+LDA8 from buf cur [12 ds_read_b128]; 32 MFMA;
// VM(0); BAR }.
//   WAR: stage target buf[cur^1] was last read in window k-1; those reads
//     feed window k-1 MFMAs (counted lgkm waits precede them) and complete
//     before window k-1's end barrier; stage is issued after it. Safe.
//   Visibility: VM(0) (each wave drains its own 4 loads) + BAR before any
//     wave reads tile k+1 in window k+1. Safe.
//   VM(0) note: issue-to-gate distance = one full window (>= ~700 cyc >= HBM
//     latency), and the co-resident block covers residual drain.
//
// T2 swizzle re-derived for 64-B K-rows (4 chunks of 16 B): LDS chunk (row,j)
// holds global k-chunk j ^ ((row>>1)&3). Read addresses: 64 lanes land
// uniformly 8-per-16B-position across the 128-B bank cycle -> conflict floor
// (SQ_LDS_BANK_CONFLICT ~0). Row terms other than fr are multiples of 16, so
// the XOR operand folds to (fr>>1)&3 -> per-thread-constant ds_read bases,
// fragment selects are compile-time immediates.
__global__ void __launch_bounds__(512, 4)
gemm256_bk32(const __bf16* __restrict__ A, const __bf16* __restrict__ W,
             const float* __restrict__ bias, float* __restrict__ out) {
  __shared__ __align__(16) char lds[65536];  // 2buf x (A 16K @0, B 16K @32768)

  const int tid  = threadIdx.x;
  const int wave = tid >> 6, lane = tid & 63;
  const int wm = wave >> 2, wn = wave & 3;   // 2 x 4 wave grid, each owns 128x64
  const int fr = lane & 15, ko = lane >> 4;  // frag row 0..15, k-chunk 0..3

  // 2D XCD grouping (bijective, 512 blocks, 8 XCDs): group g owns bm in
  // [(g&3)*8,+8), bn in [(g>>2)*8,+8). All 512 blocks co-resident at 2/CU.
  const int swzid = ((blockIdx.x & 7) << 6) + (blockIdx.x >> 3);
  const int g = swzid >> 6, w = swzid & 63;
  const int bm = ((g & 3) << 3) + (w & 7);
  const int bn = ((g >> 2) << 3) + (w >> 3);
  const int brow = bm << 8, bcol = bn << 8;

  // Staging: tile = 256 rows x 32 k = 16 KB = 1024 16B-chunks per operand.
  // Thread t covers chunks t (rows 0..127) and t+512 (rows 128..255):
  // row0 = t>>2, j = t&3; global k-chunk = j ^ ((row0>>1)&3) (same for
  // row0+128 since 64 mod 4 == 0). Dest is wave-uniform (HW adds lane*16).
  const int r0 = tid >> 2;
  const int kg = ((tid & 3) ^ ((r0 >> 1) & 3)) << 4;
  const char* aSrc = (const char*)A + (size_t)(brow + r0) * (K_DIM * 2) + kg;
  const char* bSrc = (const char*)W + (size_t)(bcol + r0) * (K_DIM * 2) + kg;
  char* dstW = lds + (wave << 10);  // wave-uniform LDS base

  // STAGE4(bb, kt): stage tile kt (A and B) into buffer bb. 4 gload_lds.
#define STAGE4(bb, kt) do {                                                    \
    const char* sa_ = aSrc + (size_t)(kt) * 64;                                \
    const char* sb_ = bSrc + (size_t)(kt) * 64;                                \
    char* da_ = dstW + (bb) * 16384;                                           \
    char* db_ = dstW + 32768 + (bb) * 16384;                                   \
    gload16(sa_, da_);                                                         \
    gload16(sa_ + 128ull * K_DIM * 2, da_ + 8192);                             \
    gload16(sb_, db_);                                                         \
    gload16(sb_ + 128ull * K_DIM * 2, db_ + 8192);                             \
  } while (0)

  // Hoisted ds_read bases. A frag (ml): row = wm*128 + ml*16 + fr ->
  // byte = wm*8192 + ml*1024 + fr*64 + ((ko ^ ((fr>>1)&3))<<4).
  const int low = ((ko ^ ((fr >> 1) & 3)) << 4) + (fr << 6);
  const char* baA0 = lds + (wm << 13) + low;
  const char* baA1 = baA0 + 16384;
  const char* baB0 = lds + 32768 + (wn << 12) + low;
  const char* baB1 = baB0 + 16384;

  bf16x8 a[8];
  bf16x8 b[4];
  f32x4 acc[8][4] = {};

#define LDA8(P) do {                                                           \
    _Pragma("unroll") for (int ml = 0; ml < 8; ++ml)                           \
      a[ml] = *(const bf16x8*)((P) + (ml << 10));                              \
  } while (0)

#define LDB4(P) do {                                                           \
    _Pragma("unroll") for (int nl = 0; nl < 4; ++nl)                           \
      b[nl] = *(const bf16x8*)((P) + (nl << 10));                              \
  } while (0)

#define MFMA32() do {                                                          \
    _Pragma("unroll") for (int ml = 0; ml < 8; ++ml)                           \
    _Pragma("unroll") for (int nl = 0; nl < 4; ++nl)                           \
      acc[ml][nl] = __builtin_amdgcn_mfma_f32_16x16x32_bf16(                   \
          a[ml], b[nl], acc[ml][nl], 0, 0, 0);                                 \
  } while (0)

#define BAR() __builtin_amdgcn_s_barrier()
#define VM0() asm volatile("s_waitcnt vmcnt(0)" ::: "memory")
#define SP1() __builtin_amdgcn_s_setprio(1)
#define SP0() __builtin_amdgcn_s_setprio(0)
#define SGB(m, n) __builtin_amdgcn_sched_group_barrier((m), (n), 0)

  // T19 interleave: VMEM(0x10) gloads first, then {b0..b3,a0} unlock 4 MFMAs,
  // each further a-read unlocks 4 more. Sums: DS 12, MFMA 32, VMEM 4.
#define ILV_S() do {                                                           \
    SGB(0x10, 4);                                                              \
    SGB(0x100, 5); SGB(0x8, 4);                                                \
    SGB(0x100, 1); SGB(0x8, 4);                                                \
    SGB(0x100, 1); SGB(0x8, 4);                                                \
    SGB(0x100, 1); SGB(0x8, 4);                                                \
    SGB(0x100, 1); SGB(0x8, 4);                                                \
    SGB(0x100, 1); SGB(0x8, 4);                                                \
    SGB(0x100, 1); SGB(0x8, 4);                                                \
    SGB(0x100, 1); SGB(0x8, 4);                                                \
  } while (0)
#define ILV_N() do {                                                           \
    SGB(0x100, 5); SGB(0x8, 4);                                                \
    SGB(0x100, 1); SGB(0x8, 4);                                                \
    SGB(0x100, 1); SGB(0x8, 4);                                                \
    SGB(0x100, 1); SGB(0x8, 4);                                                \
    SGB(0x100, 1); SGB(0x8, 4);                                                \
    SGB(0x100, 1); SGB(0x8, 4);                                                \
    SGB(0x100, 1); SGB(0x8, 4);                                                \
    SGB(0x100, 1); SGB(0x8, 4);                                                \
  } while (0)

  // WINDOW(bb, kts, stage?): read buf bb, optionally stage tile kts -> bb^1.
#define WINDOW_S(bb, kts, BA, BB) do {                                         \
    SP1();                                                                     \
    STAGE4(bb ^ 1, kts);                                                       \
    LDB4(BB); LDA8(BA);                                                        \
    MFMA32();                                                                  \
    ILV_S();                                                                   \
    SP0(); VM0(); BAR();                                                       \
  } while (0)

  // Prologue: stage tile 0 -> buf0.
  STAGE4(0, 0);
  VM0();
  BAR();

  for (int i = 0; i < 63; ++i) {
    const int k = 2 * i;
    WINDOW_S(0, k + 1, baA0, baB0);
    WINDOW_S(1, k + 2, baA1, baB1);
  }
  // Window 126: read buf0 (tile 126), stage tile 127 -> buf1.
  WINDOW_S(0, 127, baA0, baB0);
  // Window 127: read buf1, no stage, no gate needed after.
  SP1();
  LDB4(baB1); LDA8(baA1);
  MFMA32();
  ILV_N();
  SP0();

  // Epilogue: C/D mapping col=lane&15, row=(lane>>4)*4+j (m89-verified), + bias.
  const int oc0 = bcol + (wn << 6) + fr;
  const int or0 = brow + (wm << 7) + (ko << 2);
  float bv[4];
#pragma unroll
  for (int nl = 0; nl < 4; ++nl) bv[nl] = bias[oc0 + nl * 16];
#pragma unroll
  for (int ml = 0; ml < 8; ++ml)
#pragma unroll
    for (int nl = 0; nl < 4; ++nl)
#pragma unroll
      for (int j = 0; j < 4; ++j)
        out[(size_t)(or0 + ml * 16 + j) * N_DIM + (oc0 + nl * 16)] =
            acc[ml][nl][j] + bv[nl];

#undef STAGE4
#undef LDA8
#undef LDB4
#undef MFMA32
#undef BAR
#undef VM0
#undef SP1
#undef SP0
#undef SGB
#undef ILV_S
#undef ILV_N
#undef WINDOW_S
}

// Safety net if d_ws is too small for bf16 copies of A and W: correct but slow.
__global__ void naive_linear(const float* __restrict__ A, const float* __restrict__ W,
                             const float* __restrict__ bias, float* __restrict__ out) {
  int n = blockIdx.y;
  int o = blockIdx.x * 256 + threadIdx.x;
  const float* a = A + (size_t)n * K_DIM;
  const float* w = W + (size_t)o * K_DIM;
  float acc = 0.f;
  for (int k = 0; k < K_DIM; ++k) acc += a[k] * w[k];
  out[(size_t)n * N_DIM + o] = acc + bias[o];
}

extern "C" void kernel_launch(void* const* d_in, const int* in_sizes, int n_in,
                              void* d_out, int out_size, void* d_ws, size_t ws_size,
                              hipStream_t stream) {
  const float* A    = (const float*)d_in[0];
  const float* W    = (const float*)d_in[1];
  const float* bias = (const float*)d_in[2];
  float* out = (float*)d_out;

  const size_t a_elems = (size_t)M_DIM * K_DIM;
  const size_t w_elems = (size_t)N_DIM * K_DIM;
  const size_t need = (a_elems + w_elems) * sizeof(unsigned short);

  if (ws_size < need) {
    naive_linear<<<dim3(N_DIM / 256, M_DIM), 256, 0, stream>>>(A, W, bias, out);
    return;
  }

  unsigned short* Abf = (unsigned short*)d_ws;
  unsigned short* Wbf = Abf + a_elems;
  const int a4 = (int)(a_elems / 4), tot4 = (int)((a_elems + w_elems) / 4);
  cvt_both<<<2048, 256, 0, stream>>>(A, W, Abf, Wbf, a4, tot4);

  gemm256_bk32<<<(M_DIM / 256) * (N_DIM / 256), 512, 0, stream>>>(
      (const __bf16*)Abf, (const __bf16*)Wbf, bias, out);
}

// Round 9
// 387.186 us; speedup vs baseline: 4.0355x; 4.0355x over previous
//
#include <hip/hip_runtime.h>
#include <hip/hip_bf16.h>
#include <cstdint>
#include <cstddef>

#define M_DIM 8192
#define K_DIM 4096
#define N_DIM 4096

typedef __bf16 bf16x8 __attribute__((ext_vector_type(8)));
typedef float  f32x4  __attribute__((ext_vector_type(4)));

__device__ __forceinline__ unsigned cvt_pk(float lo, float hi) {
  unsigned r;
  asm("v_cvt_pk_bf16_f32 %0, %1, %2" : "=v"(r) : "v"(lo), "v"(hi));  // RNE
  return r;
}

// FUSED fp32->bf16 + 256x256-tile BK=64 GEMM (round 9).
//
// ROUND-9 CHANGES (evidence: r8 spill disaster proves 2 waves/SIMD is the
// occupancy ceiling at 128-AGPR acc -> r7 is the local optimum of its family;
// the cvt pass is 40 us of pure HBM time that fusion can eliminate):
//  1. Staging is now reg-staged fp32: global float4 loads -> v_cvt_pk_bf16_f32
//     -> swizzled ds_write_b128 (both-sides swizzle, rule 21). No separate
//     cvt kernel; ONE dispatch total.
//  2. k2-outer fragment loop with reload (a[4], b[4] vs a[4][2], b[4][2]):
//     same 24 ds_reads per K-tile, frees 64 VGPR for staging in flight.
//  3. One window per K-tile (64 barriers total, half of r7); A and B staging
//     batches time-share 32 VGPRs (A cvt'd at window start, B issued then
//     cvt'd mid-window, next A issued after). Load waits are compiler-counted
//     vmcnt (no hand vmcnt on the load path at all).
//
// Window t (bb = t&1), steady state:
//   [qa holds fp32 A(t+1), issued mid-window t-1]
//   CVTW(qa -> buf bb^1 A)            ; frees qa regs
//   ISSUE(qb <- B(t+1))               ; 8 float4 loads
//   COMPUTE half k2=0 on buf bb       ; 12 ds_read + 32 MFMA
//   CVTW(qb -> buf bb^1 B)            ; compiler vmcnt-waits qb (~1200cy old)
//   ISSUE(qa <- A(t+2))
//   COMPUTE half k2=1 on buf bb
//   s_waitcnt lgkmcnt(0); s_barrier   ; drain ds_writes -> tile t+1 visible
// WAR safety: writes target buf bb^1, whose tile t-1 reads completed before
// window t-1's barrier (each read feeds a same-window MFMA whose counted
// lgkm wait precedes the barrier). Reads of tile t+1 happen in window t+1,
// after the lgkm(0)+barrier above. In-flight staging regs: 32 peak (SGB
// places each ISSUE after the CVTW that frees the previous batch).
//
// LDS layout identical to r7 (so ds_read bases unchanged): per buf bb at
// bb*65536: A halves at +0/+16384, B at +32768/+49152; row r at rh*128;
// 16B-chunk c holds k-chunk c ^ (rh&7). Writes produce exactly this:
// thread t covers rows r0=t>>2 and r0+128, k-seg (t&3)*16 f32; chunk pair
// (kseg*2)^s, (kseg*2+1)^s with s=r0&7 (byte offsets wb0, wb0^16).
__global__ void __launch_bounds__(512, 2)
gemm_fused(const float* __restrict__ A, const float* __restrict__ W,
           const float* __restrict__ bias, float* __restrict__ out) {
  __shared__ __align__(16) char lds[131072];

  const int tid  = threadIdx.x;
  const int wave = tid >> 6, lane = tid & 63;
  const int wm = wave >> 2, wn = wave & 3;   // 2 x 4 wave grid, each owns 128x64
  const int fr = lane & 15, ko = lane >> 4;

  // 2D XCD grouping (bijective, 512 blocks, 8 XCDs): group g owns bm in
  // [(g&3)*8,+8), bn in [(g>>2)*8,+8) -> per-K-step active set L2-resident.
  const int swzid = ((blockIdx.x & 7) << 6) + (blockIdx.x >> 3);
  const int g = swzid >> 6, w = swzid & 63;
  const int bm = ((g & 3) << 3) + (w & 7);
  const int bn = ((g >> 2) << 3) + (w >> 3);
  const int brow = bm << 8, bcol = bn << 8;

  // Staging geometry (fp32): thread t loads rows r0, r0+128 x 16 f32 at kseg.
  const int r0   = tid >> 2;
  const int kseg = tid & 3;
  const float* aS0 = A + (size_t)(brow + r0) * K_DIM + kseg * 16;
  const float* aS1 = aS0 + (size_t)128 * K_DIM;
  const float* bS0 = W + (size_t)(bcol + r0) * K_DIM + kseg * 16;
  const float* bS1 = bS0 + (size_t)128 * K_DIM;
  const int wb0 = r0 * 128 + ((((kseg * 2) ^ (r0 & 7))) << 4);  // chunk pair
  const int wb1 = wb0 ^ 16;                                     // (kseg*2+1)^s

#define ISSUE(q, S0, S1, kt) do {                                              \
    const float4* p0_ = (const float4*)((S0) + (size_t)(kt) * 64);             \
    const float4* p1_ = (const float4*)((S1) + (size_t)(kt) * 64);             \
    q[0] = p0_[0]; q[1] = p0_[1]; q[2] = p0_[2]; q[3] = p0_[3];                \
    q[4] = p1_[0]; q[5] = p1_[1]; q[6] = p1_[2]; q[7] = p1_[3];                \
  } while (0)

  // cvt 32 f32 -> 16 bf16x2 and write 4x b128 into region (A:0 / B:32768).
#define CVTW(q, regionoff, bb) do {                                            \
    char* b_ = lds + (regionoff) + (bb) * 65536;                               \
    uint4 w_;                                                                  \
    w_.x = cvt_pk(q[0].x, q[0].y); w_.y = cvt_pk(q[0].z, q[0].w);              \
    w_.z = cvt_pk(q[1].x, q[1].y); w_.w = cvt_pk(q[1].z, q[1].w);              \
    *(uint4*)(b_ + wb0) = w_;                                                  \
    w_.x = cvt_pk(q[2].x, q[2].y); w_.y = cvt_pk(q[2].z, q[2].w);              \
    w_.z = cvt_pk(q[3].x, q[3].y); w_.w = cvt_pk(q[3].z, q[3].w);              \
    *(uint4*)(b_ + wb1) = w_;                                                  \
    w_.x = cvt_pk(q[4].x, q[4].y); w_.y = cvt_pk(q[4].z, q[4].w);              \
    w_.z = cvt_pk(q[5].x, q[5].y); w_.w = cvt_pk(q[5].z, q[5].w);              \
    *(uint4*)(b_ + 16384 + wb0) = w_;                                          \
    w_.x = cvt_pk(q[6].x, q[6].y); w_.y = cvt_pk(q[6].z, q[6].w);              \
    w_.z = cvt_pk(q[7].x, q[7].y); w_.w = cvt_pk(q[7].z, q[7].w);              \
    *(uint4*)(b_ + 16384 + wb1) = w_;                                          \
  } while (0)

  // Hoisted ds_read bases (row&7 == fr&7 for all fragment rows).
  const int low0 = (ko << 4) ^ ((fr & 7) << 4);
  const int low1 = low0 ^ 64;
  const char* baA[2][2];  // [bb][k2] -- constant-indexed only
  const char* baB[2][2];
  baA[0][0] = lds + (wm << 14) + (fr << 7) + low0;
  baA[0][1] = lds + (wm << 14) + (fr << 7) + low1;
  baA[1][0] = baA[0][0] + 65536;
  baA[1][1] = baA[0][1] + 65536;
  baB[0][0] = lds + 32768 + (wn << 13) + (fr << 7) + low0;
  baB[0][1] = lds + 32768 + (wn << 13) + (fr << 7) + low1;
  baB[1][0] = baB[0][0] + 65536;
  baB[1][1] = baB[0][1] + 65536;

  float4 qa[8], qb[8];     // staging registers (constant-indexed)
  f32x4 acc[8][4] = {};

  // One half-K-tile (one k2): 4 b-reads, 4+4 a-reads (mh0, mh1), 32 MFMA.
#define COMPUTE_HALF(bb, k2) do {                                              \
    bf16x8 bfr[4], afr[4];                                                     \
    _Pragma("unroll") for (int j = 0; j < 4; ++j)                              \
      bfr[j] = *(const bf16x8*)(baB[bb][k2] + (j << 11));                      \
    _Pragma("unroll") for (int j = 0; j < 4; ++j)                              \
      afr[j] = *(const bf16x8*)(baA[bb][k2] + (j << 11));                      \
    _Pragma("unroll") for (int ml = 0; ml < 4; ++ml)                           \
    _Pragma("unroll") for (int nl = 0; nl < 4; ++nl)                           \
      acc[ml][nl] = __builtin_amdgcn_mfma_f32_16x16x32_bf16(                   \
          afr[ml], bfr[nl], acc[ml][nl], 0, 0, 0);                             \
    _Pragma("unroll") for (int j = 0; j < 4; ++j)                              \
      afr[j] = *(const bf16x8*)(baA[bb][k2] + 8192 + (j << 11));               \
    _Pragma("unroll") for (int ml = 0; ml < 4; ++ml)                           \
    _Pragma("unroll") for (int nl = 0; nl < 4; ++nl)                           \
      acc[4 + ml][nl] = __builtin_amdgcn_mfma_f32_16x16x32_bf16(               \
          afr[ml], bfr[nl], acc[4 + ml][nl], 0, 0, 0);                         \
  } while (0)

#define SGB(m, n) __builtin_amdgcn_sched_group_barrier((m), (n), 0)
  // Per-half schedule: reads+MFMA lead; cvt(VALU)+ds_write nest inside; the
  // 8 VMEM issues come AFTER the writes (so the freed batch's regs are
  // reused -> staging peak stays 32 VGPR). Sums/half: DSR 12, MFMA 32,
  // VALU 16, DSW 4, VMEM 8.
#define SGB_HALF() do {                                                        \
    SGB(0x100, 5); SGB(0x8, 4);                                                \
    SGB(0x2, 16);  SGB(0x200, 4); SGB(0x20, 8);                                \
    SGB(0x100, 1); SGB(0x8, 4);  SGB(0x100, 1); SGB(0x8, 4);                   \
    SGB(0x100, 1); SGB(0x8, 4);  SGB(0x100, 1); SGB(0x8, 4);                   \
    SGB(0x100, 1); SGB(0x8, 4);  SGB(0x100, 1); SGB(0x8, 4);                   \
    SGB(0x100, 1); SGB(0x8, 4);                                                \
  } while (0)

#define BARD() do { asm volatile("s_waitcnt lgkmcnt(0)" ::: "memory");         \
                    __builtin_amdgcn_s_barrier(); } while (0)

  // Steady window: reads tile kt from buf bb; writes tile kt+1 -> buf bb^1;
  // issues B(kt+1) and A(kt+2).
#define WIN(bb, kt) do {                                                       \
    CVTW(qa, 0, (bb) ^ 1);                                                     \
    ISSUE(qb, bS0, bS1, (kt) + 1);                                             \
    COMPUTE_HALF(bb, 0);                                                       \
    SGB_HALF();                                                                \
    CVTW(qb, 32768, (bb) ^ 1);                                                 \
    ISSUE(qa, aS0, aS1, (kt) + 2);                                             \
    COMPUTE_HALF(bb, 1);                                                       \
    SGB_HALF();                                                                \
    BARD();                                                                    \
  } while (0)

  // Prologue: tile 0 -> buf0 (fp32 loads + cvt), A(1) in flight.
  ISSUE(qa, aS0, aS1, 0);
  ISSUE(qb, bS0, bS1, 0);
  CVTW(qa, 0, 0);
  CVTW(qb, 32768, 0);
  ISSUE(qa, aS0, aS1, 1);
  BARD();

  for (int i = 0; i < 31; ++i) {
    const int kt = 2 * i;
    WIN(0, kt);
    WIN(1, kt + 1);
  }
  // Window 62 (bb=0): writes tile 63 -> buf1; no A(64) issue (OOB).
  CVTW(qa, 0, 1);
  ISSUE(qb, bS0, bS1, 63);
  COMPUTE_HALF(0, 0);
  SGB_HALF();
  CVTW(qb, 32768, 1);
  COMPUTE_HALF(0, 1);
  SGB_HALF();
  BARD();
  // Window 63 (bb=1): compute only.
  COMPUTE_HALF(1, 0);
  COMPUTE_HALF(1, 1);

  // Epilogue: C/D mapping col=lane&15, row=(lane>>4)*4+j (m89-verified), + bias.
  const int oc0 = bcol + (wn << 6) + fr;
  const int or0 = brow + (wm << 7) + (ko << 2);
  float bv[4];
#pragma unroll
  for (int nl = 0; nl < 4; ++nl) bv[nl] = bias[oc0 + nl * 16];
#pragma unroll
  for (int ml = 0; ml < 8; ++ml)
#pragma unroll
    for (int nl = 0; nl < 4; ++nl)
#pragma unroll
      for (int j = 0; j < 4; ++j)
        out[(size_t)(or0 + ml * 16 + j) * N_DIM + (oc0 + nl * 16)] =
            acc[ml][nl][j] + bv[nl];

#undef ISSUE
#undef CVTW
#undef COMPUTE_HALF
#undef SGB
#undef SGB_HALF
#undef BARD
#undef WIN
}

extern "C" void kernel_launch(void* const* d_in, const int* in_sizes, int n_in,
                              void* d_out, int out_size, void* d_ws, size_t ws_size,
                              hipStream_t stream) {
  const float* A    = (const float*)d_in[0];
  const float* W    = (const float*)d_in[1];
  const float* bias = (const float*)d_in[2];
  float* out = (float*)d_out;
  (void)d_ws; (void)ws_size; (void)in_sizes; (void)n_in; (void)out_size;

  gemm_fused<<<(M_DIM / 256) * (N_DIM / 256), 512, 0, stream>>>(A, W, bias, out);
}

// Round 10
// 290.381 us; speedup vs baseline: 5.3808x; 1.3334x over previous
//
#include <hip/hip_runtime.h>
#include <hip/hip_bf16.h>
#include <cstdint>
#include <cstddef>

#define M_DIM 8192
#define K_DIM 4096
#define N_DIM 4096

typedef __bf16 bf16x8 __attribute__((ext_vector_type(8)));
typedef float  f32x16 __attribute__((ext_vector_type(16)));

__device__ __forceinline__ unsigned short f32_to_bf16_rne(float f) {
  unsigned int u = __builtin_bit_cast(unsigned int, f);
  u += 0x7FFFu + ((u >> 16) & 1u);
  return (unsigned short)(u >> 16);
}

// Single fused fp32->bf16 conversion for both A and W (one launch).
__global__ void __launch_bounds__(256) cvt_both(const float* __restrict__ A,
                                                const float* __restrict__ W,
                                                unsigned short* __restrict__ Abf,
                                                unsigned short* __restrict__ Wbf,
                                                int a4, int tot4) {
  int i = blockIdx.x * blockDim.x + threadIdx.x;
  int stride = gridDim.x * blockDim.x;
  for (; i < tot4; i += stride) {
    const float4* s = (i < a4) ? &reinterpret_cast<const float4*>(A)[i]
                               : &reinterpret_cast<const float4*>(W)[i - a4];
    ushort4* d = (i < a4) ? &reinterpret_cast<ushort4*>(Abf)[i]
                          : &reinterpret_cast<ushort4*>(Wbf)[i - a4];
    float4 v = *s;
    ushort4 o;
    o.x = f32_to_bf16_rne(v.x);
    o.y = f32_to_bf16_rne(v.y);
    o.z = f32_to_bf16_rne(v.z);
    o.w = f32_to_bf16_rne(v.w);
    *d = o;
  }
}

__device__ __forceinline__ void gload16(const void* g, void* l) {
  __builtin_amdgcn_global_load_lds((const __attribute__((address_space(1))) void*)g,
                                   (__attribute__((address_space(3))) void*)l, 16, 0, 0);
}

// 256x256-tile, BK=64, 8-wave (2Mx4N), 4-window pipelined GEMM.
//
// ROUND-10 CHANGE vs r7 (evidence: r9 fusion lost 245 us -> reverted; r7 is
// the structural local optimum at 59.5% MfmaUtil of the 16x16 pipe): swap
// MFMA 16x16x32 -> 32x32x16. Pipe ceiling 2075 -> 2382 TF (m06/m119), MFMA
// instruction count halves (16/window). LDS BYTE IMAGE, staging, stage
// slots, VM gates, and the WAR/visibility audit are IDENTICAL to r7 --
// only the LDS readers and the epilogue mapping change.
//
// Fragment layouts (32x32x16 bf16):
//   A operand: lane reads A row (lane&31), k-group (lane>>5)*8, 8 contig
//     bf16 (natural extension of the 16x16x32 mapping validated in r1-r7).
//   B operand: lane reads B col (lane&31) = W row, same k-group.
//   C/D: col = lane&31, row = (reg&3) + 8*(reg>>2) + 4*(lane>>5)
//     [m74/m101-verified].
// Per wave (128x64): 4 m-tiles x 2 n-tiles of 32x32; acc = 8 x f32x16 =
// 128 AGPR (same budget as r7). W1/W3: mt{0,1} x nt{0,1} (16 DSR, 16 MFMA);
// W2/W4: mt{2,3} x nt{0,1}, B persists (8 DSR, 16 MFMA).
//
// ds_read addressing: byte = bb*65536 + [A:0|B:32768] + row*128 +
//   (((ks*2 + (lane>>5)) ^ (row&7))<<4), row = base + (lane&31), row&7 =
//   lane&7. Conflict check: lanes 0-31 (fixed chunk, rows 0-31): each 8-row
//   group's XOR spreads across all 32 banks -> conflict-free (r7-equivalent).
//
// Schedule/gates (verbatim r7): stage slots W1: b1.A<-kb+1 | W2: b0.B<-kb+2 |
// W3: b0.A<-kb+2 | W4: b1.B<-kb+3; VM(4) end-W2 (buf1(kb+1) landed, oldest
// 12 of 16) and end-W4 (buf0(kb+2) landed, oldest 8 of 12). Every ds_read
// feeds a same-window MFMA whose counted lgkm wait precedes the end barrier
// -> reads complete before any wave crosses BAR -> stages are WAR-safe.
__global__ void __launch_bounds__(512, 2)
gemm256_32x32(const __bf16* __restrict__ A, const __bf16* __restrict__ W,
              const float* __restrict__ bias, float* __restrict__ out) {
  __shared__ __align__(16) char lds[131072];

  const int tid  = threadIdx.x;
  const int wave = tid >> 6, lane = tid & 63;
  const int wm = wave >> 2, wn = wave & 3;   // 2 x 4 wave grid, each owns 128x64
  const int l31 = lane & 31, hi = lane >> 5, s7 = lane & 7;

  // 2D XCD grouping (bijective, 512 blocks, 8 XCDs): group g owns bm in
  // [(g&3)*8,+8), bn in [(g>>2)*8,+8); per-K-step active set L2-resident.
  const int swzid = ((blockIdx.x & 7) << 6) + (blockIdx.x >> 3);
  const int g = swzid >> 6, w = swzid & 63;
  const int bm = ((g & 3) << 3) + (w & 7);
  const int bn = ((g >> 2) << 3) + (w >> 3);
  const int brow = bm << 8, bcol = bn << 8;

  // Staging (identical bytes to r7): half-tile = 128 rows x 64 k (16 KiB),
  // 512 threads x 2 gload16; T2 swizzle via pre-swizzled global source.
  const int r0 = tid >> 3;
  const int jc = (((tid & 7) ^ (r0 & 7)) << 4);
  const char* aSrc = (const char*)A + (size_t)(brow + r0) * (K_DIM * 2) + jc;
  const char* bSrc = (const char*)W + (size_t)(bcol + r0) * (K_DIM * 2) + jc;
  char* dstW = lds + (wave << 10);  // wave-uniform LDS base

#define STAGE(ms, h, bb, kt) do {                                              \
    const char* s_ = ((ms) ? bSrc : aSrc)                                      \
        + (size_t)(h) * (128ull * K_DIM * 2) + (size_t)(kt) * 128;             \
    char* d_ = dstW + (bb) * 65536 + (ms) * 32768 + (h) * 16384;               \
    gload16(s_, d_);                                                           \
    gload16(s_ + 64ull * K_DIM * 2, d_ + 8192);                                \
  } while (0)

  // Per-thread constant low bits for the 4 k-steps (chunk = ks*2 + hi).
  const int lo0 = ((0 + hi) ^ s7) << 4;
  const int lo1 = ((2 + hi) ^ s7) << 4;
  const int lo2 = ((4 + hi) ^ s7) << 4;
  const int lo3 = ((6 + hi) ^ s7) << 4;
  const char* pA = lds + (wm << 14) + (l31 << 7);           // + mt*4096 + lo
  const char* pB = lds + 32768 + (wn << 13) + (l31 << 7);   // + nt*4096 + lo

#define RA(bb, mt, LO) (*(const bf16x8*)(pA + (bb) * 65536 + (mt) * 4096 + (LO)))
#define RB(bb, nt, LO) (*(const bf16x8*)(pB + (bb) * 65536 + (nt) * 4096 + (LO)))

  bf16x8 af[2][4], bf[2][4];   // [tile][ks], constant-indexed only
  f32x16 acc[4][2] = {};       // [mt][nt]

  // Reads ordered per-ks {b0,b1,a0,a1} so each SGB {4 DSR, 4 MFMA} group is
  // dependency-feasible.
#define RD_W13(bb) do {                                                        \
    bf[0][0]=RB(bb,0,lo0); bf[1][0]=RB(bb,1,lo0); af[0][0]=RA(bb,0,lo0); af[1][0]=RA(bb,1,lo0); \
    bf[0][1]=RB(bb,0,lo1); bf[1][1]=RB(bb,1,lo1); af[0][1]=RA(bb,0,lo1); af[1][1]=RA(bb,1,lo1); \
    bf[0][2]=RB(bb,0,lo2); bf[1][2]=RB(bb,1,lo2); af[0][2]=RA(bb,0,lo2); af[1][2]=RA(bb,1,lo2); \
    bf[0][3]=RB(bb,0,lo3); bf[1][3]=RB(bb,1,lo3); af[0][3]=RA(bb,0,lo3); af[1][3]=RA(bb,1,lo3); \
  } while (0)

#define RD_W24(bb) do {                                                        \
    af[0][0]=RA(bb,2,lo0); af[1][0]=RA(bb,3,lo0);                              \
    af[0][1]=RA(bb,2,lo1); af[1][1]=RA(bb,3,lo1);                              \
    af[0][2]=RA(bb,2,lo2); af[1][2]=RA(bb,3,lo2);                              \
    af[0][3]=RA(bb,2,lo3); af[1][3]=RA(bb,3,lo3);                              \
  } while (0)

#define MM(mbase) do {                                                         \
    _Pragma("unroll") for (int ks = 0; ks < 4; ++ks)                           \
    _Pragma("unroll") for (int mt = 0; mt < 2; ++mt)                           \
    _Pragma("unroll") for (int nt = 0; nt < 2; ++nt)                           \
      acc[(mbase) + mt][nt] = __builtin_amdgcn_mfma_f32_32x32x16_bf16(         \
          af[mt][ks], bf[nt][ks], acc[(mbase) + mt][nt], 0, 0, 0);             \
  } while (0)

#define BAR() __builtin_amdgcn_s_barrier()
#define VM(n) asm volatile("s_waitcnt vmcnt(" #n ")" ::: "memory")
#define SP1() __builtin_amdgcn_s_setprio(1)
#define SP0() __builtin_amdgcn_s_setprio(0)
#define SGB(m, n) __builtin_amdgcn_sched_group_barrier((m), (n), 0)

  // T19 interleave. W1/W3: 16 DSR, 16 MFMA, 4 VMEM; W2/W4: 8 DSR, 16 MFMA, 4 VMEM.
#define ILV16() do {                                                           \
    SGB(0x100, 4); SGB(0x8, 4); SGB(0x10, 2);                                  \
    SGB(0x100, 4); SGB(0x8, 4); SGB(0x10, 2);                                  \
    SGB(0x100, 4); SGB(0x8, 4);                                                \
    SGB(0x100, 4); SGB(0x8, 4);                                                \
  } while (0)
#define ILV8() do {                                                            \
    SGB(0x100, 2); SGB(0x8, 4); SGB(0x10, 2);                                  \
    SGB(0x100, 2); SGB(0x8, 4); SGB(0x10, 2);                                  \
    SGB(0x100, 2); SGB(0x8, 4);                                                \
    SGB(0x100, 2); SGB(0x8, 4);                                                \
  } while (0)

  // Prologue: buf0 <- k0 (all 4 halves), buf1 <- k1 (B0,B1). 12 outstanding;
  // VM(4) -> oldest 8 (= all of buf0 k0) landed. b1.A staged at iter-0 W1.
  STAGE(1, 0, 0, 0);
  STAGE(1, 1, 0, 0);
  STAGE(0, 0, 0, 0);
  STAGE(0, 1, 0, 0);
  STAGE(1, 0, 1, 1);
  STAGE(1, 1, 1, 1);
  VM(4);
  BAR();

  for (int i = 0; i < 31; ++i) {
    const int kb = 2 * i;
    // W1: mt{0,1} x nt{0,1} on buf0 | stage b1.A0,A1 <- kb+1
    SP1();
    RD_W13(0);
    STAGE(0, 0, 1, kb + 1); STAGE(0, 1, 1, kb + 1);
    MM(0);
    ILV16();
    SP0(); BAR();
    // W2: mt{2,3} on buf0 | stage b0.B0,B1 <- kb+2 | VM(4): buf1(kb+1) ready
    SP1();
    RD_W24(0);
    STAGE(1, 0, 0, kb + 2); STAGE(1, 1, 0, kb + 2);
    MM(2);
    ILV8();
    SP0(); VM(4); BAR();
    // W3: mt{0,1} on buf1 | stage b0.A0,A1 <- kb+2
    SP1();
    RD_W13(1);
    STAGE(0, 0, 0, kb + 2); STAGE(0, 1, 0, kb + 2);
    MM(0);
    ILV16();
    SP0(); BAR();
    // W4: mt{2,3} on buf1 | stage b1.B0,B1 <- kb+3 | VM(4): buf0(kb+2) ready
    SP1();
    RD_W24(1);
    STAGE(1, 0, 1, kb + 3); STAGE(1, 1, 1, kb + 3);
    MM(2);
    ILV8();
    SP0(); VM(4); BAR();
  }

  // Peel (kb=62): stage only b1.A <- k63 at W1; VM(0) at end-W2 drains the
  // 8 outstanding (prev-W4 b1.B: 4, W1 b1.A: 4) = all of buf1 k63.
  RD_W13(0);
  STAGE(0, 0, 1, 63); STAGE(0, 1, 1, 63);
  MM(0); BAR();
  RD_W24(0);
  MM(2); VM(0); BAR();
  RD_W13(1);
  MM(0); BAR();
  RD_W24(1);
  MM(2);

  // Epilogue: C/D col = lane&31, row = (reg&3) + 8*(reg>>2) + 4*(lane>>5)
  // [m74/m101-verified], + bias.
  const int oc0 = bcol + (wn << 6) + l31;
  const int or0 = brow + (wm << 7) + (hi << 2);
  float bv[2];
#pragma unroll
  for (int nt = 0; nt < 2; ++nt) bv[nt] = bias[oc0 + nt * 32];
#pragma unroll
  for (int mt = 0; mt < 4; ++mt)
#pragma unroll
    for (int nt = 0; nt < 2; ++nt)
#pragma unroll
      for (int j = 0; j < 16; ++j) {
        int row = or0 + mt * 32 + (j & 3) + ((j >> 2) << 3);
        out[(size_t)row * N_DIM + (oc0 + nt * 32)] = acc[mt][nt][j] + bv[nt];
      }

#undef STAGE
#undef RA
#undef RB
#undef RD_W13
#undef RD_W24
#undef MM
#undef BAR
#undef VM
#undef SP1
#undef SP0
#undef SGB
#undef ILV16
#undef ILV8
}

// Safety net if d_ws is too small for bf16 copies of A and W: correct but slow.
__global__ void naive_linear(const float* __restrict__ A, const float* __restrict__ W,
                             const float* __restrict__ bias, float* __restrict__ out) {
  int n = blockIdx.y;
  int o = blockIdx.x * 256 + threadIdx.x;
  const float* a = A + (size_t)n * K_DIM;
  const float* w = W + (size_t)o * K_DIM;
  float acc = 0.f;
  for (int k = 0; k < K_DIM; ++k) acc += a[k] * w[k];
  out[(size_t)n * N_DIM + o] = acc + bias[o];
}

extern "C" void kernel_launch(void* const* d_in, const int* in_sizes, int n_in,
                              void* d_out, int out_size, void* d_ws, size_t ws_size,
                              hipStream_t stream) {
  const float* A    = (const float*)d_in[0];
  const float* W    = (const float*)d_in[1];
  const float* bias = (const float*)d_in[2];
  float* out = (float*)d_out;

  const size_t a_elems = (size_t)M_DIM * K_DIM;
  const size_t w_elems = (size_t)N_DIM * K_DIM;
  const size_t need = (a_elems + w_elems) * sizeof(unsigned short);

  if (ws_size < need) {
    naive_linear<<<dim3(N_DIM / 256, M_DIM), 256, 0, stream>>>(A, W, bias, out);
    return;
  }

  unsigned short* Abf = (unsigned short*)d_ws;
  unsigned short* Wbf = Abf + a_elems;
  const int a4 = (int)(a_elems / 4), tot4 = (int)((a_elems + w_elems) / 4);
  cvt_both<<<2048, 256, 0, stream>>>(A, W, Abf, Wbf, a4, tot4);

  gemm256_32x32<<<(M_DIM / 256) * (N_DIM / 256), 512, 0, stream>>>(
      (const __bf16*)Abf, (const __bf16*)Wbf, bias, out);
}

// Round 11
// 260.523 us; speedup vs baseline: 5.9975x; 1.1146x over previous
//
#include <hip/hip_runtime.h>
#include <hip/hip_bf16.h>
#include <cstdint>
#include <cstddef>

#define M_DIM 8192
#define K_DIM 4096
#define N_DIM 4096

typedef __bf16 bf16x8 __attribute__((ext_vector_type(8)));
typedef float  f32x4  __attribute__((ext_vector_type(4)));

__device__ __forceinline__ unsigned short f32_to_bf16_rne(float f) {
  unsigned int u = __builtin_bit_cast(unsigned int, f);
  u += 0x7FFFu + ((u >> 16) & 1u);
  return (unsigned short)(u >> 16);
}

// Single fused fp32->bf16 conversion for both A and W (one launch).
__global__ void __launch_bounds__(256) cvt_both(const float* __restrict__ A,
                                                const float* __restrict__ W,
                                                unsigned short* __restrict__ Abf,
                                                unsigned short* __restrict__ Wbf,
                                                int a4, int tot4) {
  int i = blockIdx.x * blockDim.x + threadIdx.x;
  int stride = gridDim.x * blockDim.x;
  for (; i < tot4; i += stride) {
    const float4* s = (i < a4) ? &reinterpret_cast<const float4*>(A)[i]
                               : &reinterpret_cast<const float4*>(W)[i - a4];
    ushort4* d = (i < a4) ? &reinterpret_cast<ushort4*>(Abf)[i]
                          : &reinterpret_cast<ushort4*>(Wbf)[i - a4];
    float4 v = *s;
    ushort4 o;
    o.x = f32_to_bf16_rne(v.x);
    o.y = f32_to_bf16_rne(v.y);
    o.z = f32_to_bf16_rne(v.z);
    o.w = f32_to_bf16_rne(v.w);
    *d = o;
  }
}

__device__ __forceinline__ void gload16(const void* g, void* l) {
  __builtin_amdgcn_global_load_lds((const __attribute__((address_space(1))) void*)g,
                                   (__attribute__((address_space(3))) void*)l, 16, 0, 0);
}

// 256x256-tile, BK=64, 8-wave (2Mx4N), 4-window pipelined GEMM.
// ROUND-11: byte-for-byte revert to the round-7 kernel (best measured state:
// GEMM 215.8 us, total 260.9 us). Round-10's 32x32x16 swap regressed
// (bank conflicts 0 -> 2.5e7, MfmaUtil 59.5 -> 50.4); reverted.
//
// Structure summary (full audits in r4-r7 history):
//  - T2 swizzle: LDS 16B-chunk (row, j) holds global k-chunk j ^ (row&7),
//    staged via pre-swizzled global source + linear gload_lds dest; ds_read
//    applies the same XOR -> 0 bank conflicts (measured).
//  - Collective read map: buf0.B last read end-W1, buf0.A end-W2, buf1.B
//    end-W3, buf1.A end-W4. Stage slots >=1 barrier after their region's
//    last collective read: W1: b1.A<-kb+1 | W2: b0.B<-kb+2 | W3: b0.A<-kb+2
//    | W4: b1.B<-kb+3. Every ds_read feeds a same-window MFMA whose counted
//    lgkm wait precedes the end barrier -> reads complete before any wave
//    crosses BAR -> stages are WAR-safe.
//  - vmcnt gates: end-W2 VM(4) -> all of buf1(kb+1) landed (oldest 12 of
//    16); end-W4 VM(4) -> all of buf0(kb+2) landed (oldest 8 of 12). Never
//    vmcnt(0) in steady state (T4).
//  - T19 sched_group_barrier interleave spreads the LDS burst across the
//    MFMA cluster; T5 setprio; T1 2D XCD grouping (FETCH 554 -> 197 MB).
__global__ void __launch_bounds__(512, 2)
gemm256_4w(const __bf16* __restrict__ A, const __bf16* __restrict__ W,
           const float* __restrict__ bias, float* __restrict__ out) {
  __shared__ __align__(16) char lds[131072];

  const int tid  = threadIdx.x;
  const int wave = tid >> 6, lane = tid & 63;
  const int wm = wave >> 2, wn = wave & 3;   // 2 x 4 wave grid, each owns 128x64
  const int fr = lane & 15, ko = lane >> 4;

  // 2D XCD grouping (bijective, 512 blocks, 8 XCDs): group g owns bm in
  // [(g&3)*8,+8), bn in [(g>>2)*8,+8); per-K-step active set ~384 KB -> L2.
  const int swzid = ((blockIdx.x & 7) << 6) + (blockIdx.x >> 3);
  const int g = swzid >> 6, w = swzid & 63;
  const int bm = ((g & 3) << 3) + (w & 7);
  const int bn = ((g >> 2) << 3) + (w >> 3);
  const int brow = bm << 8, bcol = bn << 8;

  // Staging: half-tile = 128 rows x 64 k (16 KiB), 512 threads x 2 gload16.
  const int r0 = tid >> 3;
  const int jc = (((tid & 7) ^ (r0 & 7)) << 4);
  const char* aSrc = (const char*)A + (size_t)(brow + r0) * (K_DIM * 2) + jc;
  const char* bSrc = (const char*)W + (size_t)(bcol + r0) * (K_DIM * 2) + jc;
  char* dstW = lds + (wave << 10);  // wave-uniform LDS base

#define STAGE(ms, h, bb, kt) do {                                              \
    const char* s_ = ((ms) ? bSrc : aSrc)                                      \
        + (size_t)(h) * (128ull * K_DIM * 2) + (size_t)(kt) * 128;             \
    char* d_ = dstW + (bb) * 65536 + (ms) * 32768 + (h) * 16384;               \
    gload16(s_, d_);                                                           \
    gload16(s_ + 64ull * K_DIM * 2, d_ + 8192);                                \
  } while (0)

  // Hoisted ds_read bases (row&7 == fr&7 for all fragment rows, so the
  // swizzle XOR folds into per-thread-constant low bits).
  const int low0 = (ko << 4) ^ ((fr & 7) << 4);
  const int low1 = low0 ^ 64;
  const char* baA[2][2];  // [bb][k2] -- constant-indexed only
  const char* baB[2][2];
  baA[0][0] = lds + (wm << 14) + (fr << 7) + low0;
  baA[0][1] = lds + (wm << 14) + (fr << 7) + low1;
  baA[1][0] = baA[0][0] + 65536;
  baA[1][1] = baA[0][1] + 65536;
  baB[0][0] = lds + 32768 + (wn << 13) + (fr << 7) + low0;
  baB[0][1] = lds + 32768 + (wn << 13) + (fr << 7) + low1;
  baB[1][0] = baB[0][0] + 65536;
  baB[1][1] = baB[0][1] + 65536;

  bf16x8 a[4][2];   // current m-half fragments (4 m-frags x 2 k-steps)
  bf16x8 b[4][2];   // 4 n-frags x 2 k-steps
  f32x4 acc[8][4] = {};

#define LDA8(bb, mh) do {                                                      \
    _Pragma("unroll") for (int ml = 0; ml < 4; ++ml) {                         \
      a[ml][0] = *(const bf16x8*)(baA[bb][0] + ((mh) << 13) + (ml << 11));     \
      a[ml][1] = *(const bf16x8*)(baA[bb][1] + ((mh) << 13) + (ml << 11)); }   \
  } while (0)

#define LDB4(bb, nh) do {                                                      \
    _Pragma("unroll") for (int nl = 0; nl < 2; ++nl) {                         \
      b[(nh) * 2 + nl][0] = *(const bf16x8*)(baB[bb][0] + ((nh) << 12) + (nl << 11)); \
      b[(nh) * 2 + nl][1] = *(const bf16x8*)(baB[bb][1] + ((nh) << 12) + (nl << 11)); } \
  } while (0)

#define MFMAQ(mh, nh) do {                                                     \
    _Pragma("unroll") for (int ml = 0; ml < 4; ++ml)                           \
    _Pragma("unroll") for (int nl = 0; nl < 2; ++nl)                           \
    _Pragma("unroll") for (int k2 = 0; k2 < 2; ++k2)                           \
      acc[(mh) * 4 + ml][(nh) * 2 + nl] = __builtin_amdgcn_mfma_f32_16x16x32_bf16( \
          a[ml][k2], b[(nh) * 2 + nl][k2], acc[(mh) * 4 + ml][(nh) * 2 + nl], 0, 0, 0); \
  } while (0)

#define BAR() __builtin_amdgcn_s_barrier()
#define VM(n) asm volatile("s_waitcnt vmcnt(" #n ")" ::: "memory")
#define SP1() __builtin_amdgcn_s_setprio(1)
#define SP0() __builtin_amdgcn_s_setprio(0)
#define SGB(m, n) __builtin_amdgcn_sched_group_barrier((m), (n), 0)

  // Interleave templates. Masks: MFMA=0x8, VMEM=0x10, DS_READ=0x100 (m137).
#define ILV16() do {                                                           \
    SGB(0x100, 6); SGB(0x8, 4);   /* b0,b1,a0 -> a0*b0/b1 */                   \
    SGB(0x100, 2); SGB(0x8, 4);   /* a1 -> a1*b0/b1 */                         \
    SGB(0x100, 2); SGB(0x8, 4);   /* a2 */                                     \
    SGB(0x10, 2);                                                              \
    SGB(0x100, 2); SGB(0x8, 4);   /* a3 */                                     \
    SGB(0x10, 2);                                                              \
    SGB(0x100, 2); SGB(0x8, 4);   /* b2 -> *b2 */                              \
    SGB(0x100, 2); SGB(0x8, 12);  /* b3 -> rest */                             \
  } while (0)
#define ILV8() do {                                                            \
    SGB(0x100, 2); SGB(0x8, 4);                                                \
    SGB(0x100, 2); SGB(0x8, 4);                                                \
    SGB(0x10, 2);                                                              \
    SGB(0x100, 2); SGB(0x8, 4);                                                \
    SGB(0x10, 2);                                                              \
    SGB(0x100, 2); SGB(0x8, 4);                                                \
    SGB(0x8, 16);                                                              \
  } while (0)

  // Prologue: buf0 <- k0 (all 4 halves), buf1 <- k1 (B0,B1). 12 outstanding;
  // VM(4) -> oldest 8 (= all of buf0 k0) landed. b1.A staged at iter-0 W1.
  STAGE(1, 0, 0, 0);
  STAGE(1, 1, 0, 0);
  STAGE(0, 0, 0, 0);
  STAGE(0, 1, 0, 0);
  STAGE(1, 0, 1, 1);
  STAGE(1, 1, 1, 1);
  VM(4);
  BAR();

  for (int i = 0; i < 31; ++i) {
    const int kb = 2 * i;
    // W1: Q(0,0)+Q(0,1) on buf0 | stage b1.A0,A1 <- kb+1
    SP1();
    LDB4(0, 0); LDA8(0, 0); LDB4(0, 1);
    STAGE(0, 0, 1, kb + 1); STAGE(0, 1, 1, kb + 1);
    MFMAQ(0, 0); MFMAQ(0, 1);
    ILV16();
    SP0(); BAR();
    // W2: Q(1,1)+Q(1,0) on buf0 | stage b0.B0,B1 <- kb+2 | VM(4): buf1 ready
    SP1();
    LDA8(0, 1);
    STAGE(1, 0, 0, kb + 2); STAGE(1, 1, 0, kb + 2);
    MFMAQ(1, 1); MFMAQ(1, 0);
    ILV8();
    SP0(); VM(4); BAR();
    // W3: Q(0,0)+Q(0,1) on buf1 | stage b0.A0,A1 <- kb+2
    SP1();
    LDB4(1, 0); LDA8(1, 0); LDB4(1, 1);
    STAGE(0, 0, 0, kb + 2); STAGE(0, 1, 0, kb + 2);
    MFMAQ(0, 0); MFMAQ(0, 1);
    ILV16();
    SP0(); BAR();
    // W4: Q(1,1)+Q(1,0) on buf1 | stage b1.B0,B1 <- kb+3 | VM(4): buf0 ready
    SP1();
    LDA8(1, 1);
    STAGE(1, 0, 1, kb + 3); STAGE(1, 1, 1, kb + 3);
    MFMAQ(1, 1); MFMAQ(1, 0);
    ILV8();
    SP0(); VM(4); BAR();
  }

  // Peel (kb=62): stage only b1.A <- k63 at W1; VM(0) at end-W2 drains the
  // 8 outstanding (prev-W4 b1.B: 4, W1 b1.A: 4) = all of buf1 k63.
  LDB4(0, 0); LDA8(0, 0); LDB4(0, 1);
  STAGE(0, 0, 1, 63); STAGE(0, 1, 1, 63);
  MFMAQ(0, 0); MFMAQ(0, 1); BAR();
  LDA8(0, 1);
  MFMAQ(1, 1); MFMAQ(1, 0); VM(0); BAR();
  LDB4(1, 0); LDA8(1, 0); LDB4(1, 1);
  MFMAQ(0, 0); MFMAQ(0, 1); BAR();
  LDA8(1, 1);
  MFMAQ(1, 1); MFMAQ(1, 0);

  // Epilogue: C/D mapping col=lane&15, row=(lane>>4)*4+j (m89-verified), + bias.
  const int oc0 = bcol + (wn << 6) + fr;
  const int or0 = brow + (wm << 7) + (ko << 2);
  float bv[4];
#pragma unroll
  for (int nl = 0; nl < 4; ++nl) bv[nl] = bias[oc0 + nl * 16];
#pragma unroll
  for (int ml = 0; ml < 8; ++ml)
#pragma unroll
    for (int nl = 0; nl < 4; ++nl)
#pragma unroll
      for (int j = 0; j < 4; ++j)
        out[(size_t)(or0 + ml * 16 + j) * N_DIM + (oc0 + nl * 16)] =
            acc[ml][nl][j] + bv[nl];

#undef STAGE
#undef LDA8
#undef LDB4
#undef MFMAQ
#undef BAR
#undef VM
#undef SP1
#undef SP0
#undef SGB
#undef ILV16
#undef ILV8
}

// Safety net if d_ws is too small for bf16 copies of A and W: correct but slow.
__global__ void naive_linear(const float* __restrict__ A, const float* __restrict__ W,
                             const float* __restrict__ bias, float* __restrict__ out) {
  int n = blockIdx.y;
  int o = blockIdx.x * 256 + threadIdx.x;
  const float* a = A + (size_t)n * K_DIM;
  const float* w = W + (size_t)o * K_DIM;
  float acc = 0.f;
  for (int k = 0; k < K_DIM; ++k) acc += a[k] * w[k];
  out[(size_t)n * N_DIM + o] = acc + bias[o];
}

extern "C" void kernel_launch(void* const* d_in, const int* in_sizes, int n_in,
                              void* d_out, int out_size, void* d_ws, size_t ws_size,
                              hipStream_t stream) {
  const float* A    = (const float*)d_in[0];
  const float* W    = (const float*)d_in[1];
  const float* bias = (const float*)d_in[2];
  float* out = (float*)d_out;

  const size_t a_elems = (size_t)M_DIM * K_DIM;
  const size_t w_elems = (size_t)N_DIM * K_DIM;
  const size_t need = (a_elems + w_elems) * sizeof(unsigned short);

  if (ws_size < need) {
    naive_linear<<<dim3(N_DIM / 256, M_DIM), 256, 0, stream>>>(A, W, bias, out);
    return;
  }

  unsigned short* Abf = (unsigned short*)d_ws;
  unsigned short* Wbf = Abf + a_elems;
  const int a4 = (int)(a_elems / 4), tot4 = (int)((a_elems + w_elems) / 4);
  cvt_both<<<2048, 256, 0, stream>>>(A, W, Abf, Wbf, a4, tot4);

  gemm256_4w<<<(M_DIM / 256) * (N_DIM / 256), 512, 0, stream>>>(
      (const __bf16*)Abf, (const __bf16*)Wbf, bias, out);
}